// Round 1
// baseline (46.578 us; speedup 1.0000x reference)
//
#include <hip/hip_runtime.h>
#include <hip/hip_bf16.h>

// Problem constants: N=64, B=1, C=256, H=W=4 -> P=16 spatial, FMAP=4096.
#define NN    64
#define CC    256
#define PP    16
#define FMAP  4096   // CC*PP
#define KCH   64     // k-chunks for the W_g matvec split

// K1: U[n] = x[n] - (W1+W2)@x[n] - b_e ;  B[n] = W2@x[n]
// grid (64, 16): blockIdx.x = n, blockIdx.y = 16-row o-chunk. 256 threads.
__global__ void k_ub(const float* __restrict__ x, const float* __restrict__ We,
                     const float* __restrict__ be,
                     float* __restrict__ U, float* __restrict__ Bm) {
    __shared__ float xs[FMAP];        // x[n], 16 KB
    __shared__ float wl[16 * 520];    // 16 W_e rows, padded stride 520 (bank-conflict-free)
    const int n  = blockIdx.x;
    const int ob = blockIdx.y;
    const int t  = threadIdx.x;

    const float* xn = x + (size_t)n * FMAP;
    #pragma unroll
    for (int k = 0; k < 16; ++k) xs[k * 256 + t] = xn[k * 256 + t];

    const float* wsrc = We + (size_t)(ob * 16) * 512;   // 16 contiguous rows of 512
    #pragma unroll
    for (int k = 0; k < 32; ++k) {
        int idx = k * 256 + t;
        int r = idx >> 9, c = idx & 511;
        wl[r * 520 + c] = wsrc[idx];
    }
    __syncthreads();

    const int ol = t >> 4, p = t & 15;
    const int o  = ob * 16 + ol;
    float accA = be[o];   // A includes b_e
    float accB = 0.0f;
    const float* wrow = &wl[ol * 520];
    #pragma unroll 8
    for (int c = 0; c < CC; ++c) {
        float xv = xs[c * PP + p];
        float w1 = wrow[c];
        float w2 = wrow[256 + c];
        accA = fmaf(w1 + w2, xv, accA);
        accB = fmaf(w2, xv, accB);
    }
    size_t oidx = (size_t)n * FMAP + o * PP + p;
    U[oidx]  = xs[o * PP + p] - accA;
    Bm[oidx] = accB;
}

// K2: agg[m] = sum_n x[n][m] / 64.  grid 16 x 256 threads.
__global__ void k_agg(const float* __restrict__ x, float* __restrict__ agg) {
    int m = blockIdx.x * 256 + threadIdx.x;
    float s = 0.0f;
    #pragma unroll 8
    for (int n = 0; n < NN; ++n) s += x[(size_t)n * FMAP + m];
    agg[m] = s * (1.0f / 64.0f);
}

// K3: edges[i*64+j] = (i==j) ? 1 : sum_p |U[j][p] - B[i][p]|.  grid 4096 x 256.
__global__ void k_dist(const float* __restrict__ U, const float* __restrict__ Bm,
                       float* __restrict__ edges) {
    const int e = blockIdx.x;
    const int i = e >> 6, j = e & 63;
    const float* Uj = U  + (size_t)j * FMAP;
    const float* Bi = Bm + (size_t)i * FMAP;
    const int t = threadIdx.x;
    float s = 0.0f;
    #pragma unroll
    for (int k = 0; k < 16; ++k) {
        int idx = k * 256 + t;
        s += fabsf(Uj[idx] - Bi[idx]);
    }
    #pragma unroll
    for (int off = 32; off; off >>= 1) s += __shfl_down(s, off, 64);
    __shared__ float wsum[4];
    if ((t & 63) == 0) wsum[t >> 6] = s;
    __syncthreads();
    if (t == 0) {
        float tot = wsum[0] + wsum[1] + wsum[2] + wsum[3];
        edges[e] = (i == j) ? 1.0f : tot;
    }
}

// K4: partial matvec: part[kb][m] = sum_{k in chunk kb} agg[k] * W_g[k][m]
// grid (4, KCH), 256 threads, float4 per thread (1024 m per block).
__global__ void k_mv(const float* __restrict__ agg, const float* __restrict__ Wg,
                     float* __restrict__ part) {
    const int t  = threadIdx.x;
    const int m0 = blockIdx.x * 1024 + t * 4;
    const int kb = blockIdx.y;
    float4 acc = make_float4(0.f, 0.f, 0.f, 0.f);
    #pragma unroll 8
    for (int r = 0; r < FMAP / KCH; ++r) {
        int k = kb * (FMAP / KCH) + r;
        float a = agg[k];
        const float4 w = *reinterpret_cast<const float4*>(Wg + (size_t)k * FMAP + m0);
        acc.x = fmaf(a, w.x, acc.x);
        acc.y = fmaf(a, w.y, acc.y);
        acc.z = fmaf(a, w.z, acc.z);
        acc.w = fmaf(a, w.w, acc.w);
    }
    *reinterpret_cast<float4*>(part + (size_t)kb * FMAP + m0) = acc;
}

// K5: rst[m] = sum_kb part[kb][m] + b_g[m]; out[n][m] = rst[m] for all n. grid 16 x 256.
__global__ void k_out(const float* __restrict__ part, const float* __restrict__ bg,
                      float* __restrict__ out) {
    int m = blockIdx.x * 256 + threadIdx.x;
    float s = bg[m];
    #pragma unroll 8
    for (int kb = 0; kb < KCH; ++kb) s += part[(size_t)kb * FMAP + m];
    #pragma unroll 4
    for (int n = 0; n < NN; ++n) out[(size_t)n * FMAP + m] = s;
}

extern "C" void kernel_launch(void* const* d_in, const int* in_sizes, int n_in,
                              void* d_out, int out_size, void* d_ws, size_t ws_size,
                              hipStream_t stream) {
    const float* x  = (const float*)d_in[0];   // (64,1,256,4,4)
    const float* We = (const float*)d_in[1];   // (256,512)
    const float* be = (const float*)d_in[2];   // (256,)
    const float* Wg = (const float*)d_in[3];   // (4096,4096)
    const float* bg = (const float*)d_in[4];   // (4096,)
    float* out   = (float*)d_out;              // [0,262144) = out, [262144,266240) = edges
    float* edges = out + (size_t)NN * FMAP;

    float* ws   = (float*)d_ws;
    float* agg  = ws;                       // 4096 floats
    float* U    = ws + FMAP;                // 262144 floats
    float* Bm   = U + (size_t)NN * FMAP;    // 262144 floats
    float* part = U;                        // reused AFTER k_dist (stream-ordered)

    k_ub  <<<dim3(NN, 16), 256, 0, stream>>>(x, We, be, U, Bm);
    k_agg <<<dim3(FMAP / 256), 256, 0, stream>>>(x, agg);
    k_dist<<<dim3(NN * NN), 256, 0, stream>>>(U, Bm, edges);
    k_mv  <<<dim3(4, KCH), 256, 0, stream>>>(agg, Wg, part);   // clobbers U (dead now)
    k_out <<<dim3(FMAP / 256), 256, 0, stream>>>(part, bg, out);
}

// Round 2
// 40.681 us; speedup vs baseline: 1.1450x; 1.1450x over previous
//
#include <hip/hip_runtime.h>
#include <hip/hip_bf16.h>

#define NN    64
#define CC    256
#define PP    16
#define FMAP  4096   // CC*PP
#define KCH   64     // k-chunks for the W_g matvec split

// ---------------------------------------------------------------------------
// K1 v2: dual register-tiled GEMM.
//   C1[o][col] = sum_k (W1+W2)[o][k] * X[k][col]   (col = n*16+p, 1024 cols)
//   C2[o][col] = sum_k  W2[o][k]     * X[k][col]
//   U[n][o][p] = x[n][o][p] - C1 - be[o];  Bm[n][o][p] = C2
// grid (8 o-tiles x 32 col-tiles) = 256 blocks, 256 threads.
// Block tile: 32 o x 32 col. Micro-tile 4x4, split-k x4 across waves.
// LDS: wts/wt2/xs each [128][32] (k-chunked by 128) = 48 KB.
// ---------------------------------------------------------------------------
__global__ __launch_bounds__(256) void k_ub(const float* __restrict__ x,
                                            const float* __restrict__ We,
                                            const float* __restrict__ be,
                                            float* __restrict__ U,
                                            float* __restrict__ Bm) {
    __shared__ float smem[3 * 4096];
    float* wts = smem;            // [kl][ol] : W1+W2
    float* wt2 = smem + 4096;     // [kl][ol] : W2
    float* xs  = smem + 8192;     // [kl][cl] : X

    const int t    = threadIdx.x;
    const int o0   = blockIdx.x * 32;
    const int col0 = blockIdx.y * 32;
    const int n0   = col0 >> 4;          // 2 n's per block

    const int kq  = t >> 6;              // split-k quarter (wave id)
    const int pos = t & 63;
    const int og  = pos >> 3;            // 0..7 -> 4 o's each
    const int cg  = pos & 7;             // 0..7 -> 4 cols each

    // W staging mapping: 32 rows x 8 segs of 16 k
    const int wol = t >> 3, wseg = t & 7;

    float acc1[4][4] = {{0.f}}, acc2[4][4] = {{0.f}};

    for (int ch = 0; ch < 2; ++ch) {
        const int kb = ch * 128;
        if (ch) __syncthreads();   // protect smem from previous compute

        // --- stage W transposed, fold Ws = W1+W2 ---
        {
            const float* wr = We + (size_t)(o0 + wol) * 512 + kb + wseg * 16;
            float w1v[16], w2v[16];
            #pragma unroll
            for (int q = 0; q < 16; q += 4) {
                *(float4*)&w1v[q] = *(const float4*)(wr + q);
                *(float4*)&w2v[q] = *(const float4*)(wr + 256 + q);
            }
            #pragma unroll
            for (int q = 0; q < 16; ++q) {
                int kl = wseg * 16 + q;
                wts[kl * 32 + wol] = w1v[q] + w2v[q];
                wt2[kl * 32 + wol] = w2v[q];
            }
        }
        // --- stage X transposed: xs[kl][nl*16+p] = x[n0+nl][kb+kl][p] ---
        #pragma unroll
        for (int i = 0; i < 4; ++i) {
            int idx4 = t * 4 + i * 1024;
            int nl = idx4 >> 11, rem = idx4 & 2047;
            int kl = rem >> 4, p = rem & 15;
            float4 v = *(const float4*)&x[(size_t)(n0 + nl) * FMAP + (kb + kl) * PP + p];
            *(float4*)&xs[kl * 32 + nl * 16 + p] = v;
        }
        __syncthreads();

        // --- compute: this wave's 32-k slice of the chunk ---
        const int kbase = kq * 32;
        #pragma unroll 8
        for (int kk = 0; kk < 32; ++kk) {
            int k = kbase + kk;
            const float4 a1 = *(const float4*)&wts[k * 32 + og * 4];
            const float4 a2 = *(const float4*)&wt2[k * 32 + og * 4];
            const float4 b  = *(const float4*)&xs [k * 32 + cg * 4];
            const float av1[4] = {a1.x, a1.y, a1.z, a1.w};
            const float av2[4] = {a2.x, a2.y, a2.z, a2.w};
            const float bv [4] = {b.x,  b.y,  b.z,  b.w};
            #pragma unroll
            for (int i2 = 0; i2 < 4; ++i2)
                #pragma unroll
                for (int j = 0; j < 4; ++j) {
                    acc1[i2][j] = fmaf(av1[i2], bv[j], acc1[i2][j]);
                    acc2[i2][j] = fmaf(av2[i2], bv[j], acc2[i2][j]);
                }
        }
        __syncthreads();
    }

    // --- split-k reduction through LDS (stride-33 pad -> conflict-free) ---
    float* red = smem;   // wts/wt2 dead; need 191*33+32 = 6335 floats < 8192
    if (kq > 0) {
        float* dst = red + ((kq - 1) * 64 + pos) * 33;
        #pragma unroll
        for (int i2 = 0; i2 < 4; ++i2)
            #pragma unroll
            for (int j = 0; j < 4; ++j) {
                dst[i2 * 4 + j]      = acc1[i2][j];
                dst[16 + i2 * 4 + j] = acc2[i2][j];
            }
    }
    __syncthreads();
    if (kq == 0) {
        #pragma unroll
        for (int q = 0; q < 3; ++q) {
            const float* s = red + (q * 64 + pos) * 33;
            #pragma unroll
            for (int i2 = 0; i2 < 4; ++i2)
                #pragma unroll
                for (int j = 0; j < 4; ++j) {
                    acc1[i2][j] += s[i2 * 4 + j];
                    acc2[i2][j] += s[16 + i2 * 4 + j];
                }
        }
        // write out: this thread's col quad is contiguous (same n, 4 p's)
        const int nl = cg >> 2;
        const int p0 = (cg * 4) & 15;
        const int n  = n0 + nl;
        #pragma unroll
        for (int i2 = 0; i2 < 4; ++i2) {
            const int o = o0 + og * 4 + i2;
            const float bias = be[o];
            const float4 xv = *(const float4*)&x[(size_t)n * FMAP + o * PP + p0];
            float4 uo, bo;
            uo.x = xv.x - acc1[i2][0] - bias;
            uo.y = xv.y - acc1[i2][1] - bias;
            uo.z = xv.z - acc1[i2][2] - bias;
            uo.w = xv.w - acc1[i2][3] - bias;
            bo.x = acc2[i2][0]; bo.y = acc2[i2][1];
            bo.z = acc2[i2][2]; bo.w = acc2[i2][3];
            *(float4*)&U [(size_t)n * FMAP + o * PP + p0] = uo;
            *(float4*)&Bm[(size_t)n * FMAP + o * PP + p0] = bo;
        }
    }
}

// K2: agg[m] = mean_n x[n][m].  grid 16 x 256 threads.
__global__ void k_agg(const float* __restrict__ x, float* __restrict__ agg) {
    int m = blockIdx.x * 256 + threadIdx.x;
    float s = 0.0f;
    #pragma unroll 8
    for (int n = 0; n < NN; ++n) s += x[(size_t)n * FMAP + m];
    agg[m] = s * (1.0f / 64.0f);
}

// ---------------------------------------------------------------------------
// K3 v2: pair-tiled distance. grid 256 = (16 i-tiles x 16 j-tiles), 4x4 pairs
// per block, 256 threads; register-tiled abs-diff, wave shuffle reduction.
// ---------------------------------------------------------------------------
__global__ __launch_bounds__(256) void k_dist(const float* __restrict__ U,
                                              const float* __restrict__ Bm,
                                              float* __restrict__ edges) {
    const int i0 = (blockIdx.x >> 4) * 4;
    const int j0 = (blockIdx.x & 15) * 4;
    const int t  = threadIdx.x;

    float acc[4][4] = {{0.f}};   // [il][jl]
    #pragma unroll
    for (int s = 0; s < 4; ++s) {
        const int m = s * 1024 + t * 4;
        float4 u[4], b[4];
        #pragma unroll
        for (int jl = 0; jl < 4; ++jl) u[jl] = *(const float4*)&U [(size_t)(j0 + jl) * FMAP + m];
        #pragma unroll
        for (int il = 0; il < 4; ++il) b[il] = *(const float4*)&Bm[(size_t)(i0 + il) * FMAP + m];
        #pragma unroll
        for (int il = 0; il < 4; ++il)
            #pragma unroll
            for (int jl = 0; jl < 4; ++jl) {
                acc[il][jl] += fabsf(u[jl].x - b[il].x) + fabsf(u[jl].y - b[il].y)
                             + fabsf(u[jl].z - b[il].z) + fabsf(u[jl].w - b[il].w);
            }
    }
    // butterfly reduce each of the 16 sums across the wave
    #pragma unroll
    for (int il = 0; il < 4; ++il)
        #pragma unroll
        for (int jl = 0; jl < 4; ++jl) {
            float v = acc[il][jl];
            #pragma unroll
            for (int msk = 1; msk < 64; msk <<= 1) v += __shfl_xor(v, msk, 64);
            acc[il][jl] = v;
        }
    __shared__ float wred[4][16];
    const int w = t >> 6;
    if ((t & 63) == 0) {
        #pragma unroll
        for (int il = 0; il < 4; ++il)
            #pragma unroll
            for (int jl = 0; jl < 4; ++jl) wred[w][il * 4 + jl] = acc[il][jl];
    }
    __syncthreads();
    if (t < 16) {
        const int il = t >> 2, jl = t & 3;
        const int i = i0 + il, j = j0 + jl;
        float v = wred[0][t] + wred[1][t] + wred[2][t] + wred[3][t];
        edges[i * 64 + j] = (i == j) ? 1.0f : v;
    }
}

// K4: partial matvec over W_g. grid (4, KCH), 256 threads, float4/thread.
__global__ void k_mv(const float* __restrict__ agg, const float* __restrict__ Wg,
                     float* __restrict__ part) {
    const int t  = threadIdx.x;
    const int m0 = blockIdx.x * 1024 + t * 4;
    const int kb = blockIdx.y;
    float4 acc = make_float4(0.f, 0.f, 0.f, 0.f);
    #pragma unroll 8
    for (int r = 0; r < FMAP / KCH; ++r) {
        int k = kb * (FMAP / KCH) + r;
        float a = agg[k];
        const float4 w = *reinterpret_cast<const float4*>(Wg + (size_t)k * FMAP + m0);
        acc.x = fmaf(a, w.x, acc.x);
        acc.y = fmaf(a, w.y, acc.y);
        acc.z = fmaf(a, w.z, acc.z);
        acc.w = fmaf(a, w.w, acc.w);
    }
    *reinterpret_cast<float4*>(part + (size_t)kb * FMAP + m0) = acc;
}

// K5: rst[m] = sum_kb part[kb][m] + b_g[m]; broadcast to 64 rows.
__global__ void k_out(const float* __restrict__ part, const float* __restrict__ bg,
                      float* __restrict__ out) {
    int m = blockIdx.x * 256 + threadIdx.x;
    float s = bg[m];
    #pragma unroll 8
    for (int kb = 0; kb < KCH; ++kb) s += part[(size_t)kb * FMAP + m];
    #pragma unroll 4
    for (int n = 0; n < NN; ++n) out[(size_t)n * FMAP + m] = s;
}

extern "C" void kernel_launch(void* const* d_in, const int* in_sizes, int n_in,
                              void* d_out, int out_size, void* d_ws, size_t ws_size,
                              hipStream_t stream) {
    const float* x  = (const float*)d_in[0];   // (64,1,256,4,4)
    const float* We = (const float*)d_in[1];   // (256,512)
    const float* be = (const float*)d_in[2];   // (256,)
    const float* Wg = (const float*)d_in[3];   // (4096,4096)
    const float* bg = (const float*)d_in[4];   // (4096,)
    float* out   = (float*)d_out;
    float* edges = out + (size_t)NN * FMAP;

    float* ws   = (float*)d_ws;
    float* agg  = ws;                       // 4096 floats
    float* U    = ws + FMAP;                // 262144 floats
    float* Bm   = U + (size_t)NN * FMAP;    // 262144 floats
    float* part = U;                        // reused AFTER k_dist (stream-ordered)

    k_ub  <<<dim3(8, 32),  256, 0, stream>>>(x, We, be, U, Bm);
    k_agg <<<dim3(FMAP / 256), 256, 0, stream>>>(x, agg);
    k_dist<<<dim3(256), 256, 0, stream>>>(U, Bm, edges);
    k_mv  <<<dim3(4, KCH), 256, 0, stream>>>(agg, Wg, part);   // clobbers U (dead now)
    k_out <<<dim3(FMAP / 256), 256, 0, stream>>>(part, bg, out);
}

// Round 3
// 27.333 us; speedup vs baseline: 1.7041x; 1.4883x over previous
//
#include <hip/hip_runtime.h>
#include <hip/hip_bf16.h>

#define NN    64
#define CC    256
#define PP    16
#define FMAP  4096   // CC*PP
#define KCH   64     // k-chunks for the W_g matvec split

// ---------------------------------------------------------------------------
// K_big: 512 blocks x 256 threads.
//   blocks [0,256):  mv role  — inline agg for its 64-k chunk, then stream W_g
//                    into part[kb][m].  HBM-bound (64 MB).
//   blocks [256,512): ub role — dual register-tiled GEMM producing U, Bm.
//                    VALU/LDS-bound; hides under the W_g stream.
// ---------------------------------------------------------------------------
__global__ __launch_bounds__(256) void k_big(const float* __restrict__ x,
                                             const float* __restrict__ We,
                                             const float* __restrict__ be,
                                             const float* __restrict__ Wg,
                                             float* __restrict__ U,
                                             float* __restrict__ Bm,
                                             float* __restrict__ part) {
    __shared__ float smem[3 * 4096];
    const int t = threadIdx.x;

    if (blockIdx.x < 256) {
        // ================= mv role =================
        const int qx = blockIdx.x & 3;    // m quarter
        const int kb = blockIdx.x >> 2;   // k chunk (64 k's)

        // inline agg[kb*64 + kl] = mean_n x[n][k]
        {
            const int kl = t & 63, q = t >> 6;
            float s = 0.f;
            #pragma unroll
            for (int nn = 0; nn < 16; ++nn)
                s += x[(size_t)(q * 16 + nn) * FMAP + kb * 64 + kl];
            smem[q * 64 + kl] = s;
        }
        __syncthreads();
        if (t < 64)
            smem[256 + t] = (smem[t] + smem[64 + t] + smem[128 + t] + smem[192 + t])
                            * (1.0f / 64.0f);
        __syncthreads();
        const float* aggs = smem + 256;

        const int m0 = qx * 1024 + t * 4;
        float4 acc = make_float4(0.f, 0.f, 0.f, 0.f);
        #pragma unroll 4
        for (int r4 = 0; r4 < 16; ++r4) {
            const float4 av = *(const float4*)&aggs[r4 * 4];
            const int k = kb * 64 + r4 * 4;
            const float4 w0 = *(const float4*)&Wg[(size_t)(k    ) * FMAP + m0];
            const float4 w1 = *(const float4*)&Wg[(size_t)(k + 1) * FMAP + m0];
            const float4 w2 = *(const float4*)&Wg[(size_t)(k + 2) * FMAP + m0];
            const float4 w3 = *(const float4*)&Wg[(size_t)(k + 3) * FMAP + m0];
            acc.x = fmaf(av.x, w0.x, acc.x); acc.y = fmaf(av.x, w0.y, acc.y);
            acc.z = fmaf(av.x, w0.z, acc.z); acc.w = fmaf(av.x, w0.w, acc.w);
            acc.x = fmaf(av.y, w1.x, acc.x); acc.y = fmaf(av.y, w1.y, acc.y);
            acc.z = fmaf(av.y, w1.z, acc.z); acc.w = fmaf(av.y, w1.w, acc.w);
            acc.x = fmaf(av.z, w2.x, acc.x); acc.y = fmaf(av.z, w2.y, acc.y);
            acc.z = fmaf(av.z, w2.z, acc.z); acc.w = fmaf(av.z, w2.w, acc.w);
            acc.x = fmaf(av.w, w3.x, acc.x); acc.y = fmaf(av.w, w3.y, acc.y);
            acc.z = fmaf(av.w, w3.z, acc.z); acc.w = fmaf(av.w, w3.w, acc.w);
        }
        *(float4*)&part[(size_t)kb * FMAP + m0] = acc;
        return;
    }

    // ================= ub role =================
    const int b    = blockIdx.x - 256;
    const int o0   = (b & 7) * 32;
    const int col0 = (b >> 3) * 32;
    const int n0   = col0 >> 4;

    float* wts = smem;            // [kl][ol] : W1+W2
    float* wt2 = smem + 4096;     // [kl][ol] : W2
    float* xs  = smem + 8192;     // [kl][cl] : X

    const int kq  = t >> 6;
    const int pos = t & 63;
    const int og  = pos >> 3;
    const int cg  = pos & 7;
    const int wol = t >> 3, wseg = t & 7;

    float acc1[4][4] = {{0.f}}, acc2[4][4] = {{0.f}};

    for (int ch = 0; ch < 2; ++ch) {
        const int kb = ch * 128;
        if (ch) __syncthreads();

        {
            const float* wr = We + (size_t)(o0 + wol) * 512 + kb + wseg * 16;
            float w1v[16], w2v[16];
            #pragma unroll
            for (int q = 0; q < 16; q += 4) {
                *(float4*)&w1v[q] = *(const float4*)(wr + q);
                *(float4*)&w2v[q] = *(const float4*)(wr + 256 + q);
            }
            #pragma unroll
            for (int q = 0; q < 16; ++q) {
                int kl = wseg * 16 + q;
                wts[kl * 32 + wol] = w1v[q] + w2v[q];
                wt2[kl * 32 + wol] = w2v[q];
            }
        }
        #pragma unroll
        for (int i = 0; i < 4; ++i) {
            int idx4 = t * 4 + i * 1024;
            int nl = idx4 >> 11, rem = idx4 & 2047;
            int kl = rem >> 4, p = rem & 15;
            float4 v = *(const float4*)&x[(size_t)(n0 + nl) * FMAP + (kb + kl) * PP + p];
            *(float4*)&xs[kl * 32 + nl * 16 + p] = v;
        }
        __syncthreads();

        const int kbase = kq * 32;
        #pragma unroll 8
        for (int kk = 0; kk < 32; ++kk) {
            int k = kbase + kk;
            const float4 a1 = *(const float4*)&wts[k * 32 + og * 4];
            const float4 a2 = *(const float4*)&wt2[k * 32 + og * 4];
            const float4 bx = *(const float4*)&xs [k * 32 + cg * 4];
            const float av1[4] = {a1.x, a1.y, a1.z, a1.w};
            const float av2[4] = {a2.x, a2.y, a2.z, a2.w};
            const float bv [4] = {bx.x, bx.y, bx.z, bx.w};
            #pragma unroll
            for (int i2 = 0; i2 < 4; ++i2)
                #pragma unroll
                for (int j = 0; j < 4; ++j) {
                    acc1[i2][j] = fmaf(av1[i2], bv[j], acc1[i2][j]);
                    acc2[i2][j] = fmaf(av2[i2], bv[j], acc2[i2][j]);
                }
        }
        __syncthreads();
    }

    float* red = smem;
    if (kq > 0) {
        float* dst = red + ((kq - 1) * 64 + pos) * 33;
        #pragma unroll
        for (int i2 = 0; i2 < 4; ++i2)
            #pragma unroll
            for (int j = 0; j < 4; ++j) {
                dst[i2 * 4 + j]      = acc1[i2][j];
                dst[16 + i2 * 4 + j] = acc2[i2][j];
            }
    }
    __syncthreads();
    if (kq == 0) {
        #pragma unroll
        for (int q = 0; q < 3; ++q) {
            const float* s = red + (q * 64 + pos) * 33;
            #pragma unroll
            for (int i2 = 0; i2 < 4; ++i2)
                #pragma unroll
                for (int j = 0; j < 4; ++j) {
                    acc1[i2][j] += s[i2 * 4 + j];
                    acc2[i2][j] += s[16 + i2 * 4 + j];
                }
        }
        const int nl = cg >> 2;
        const int p0 = (cg * 4) & 15;
        const int n  = n0 + nl;
        #pragma unroll
        for (int i2 = 0; i2 < 4; ++i2) {
            const int o = o0 + og * 4 + i2;
            const float bias = be[o];
            const float4 xv = *(const float4*)&x[(size_t)n * FMAP + o * PP + p0];
            float4 uo, bo;
            uo.x = xv.x - acc1[i2][0] - bias;
            uo.y = xv.y - acc1[i2][1] - bias;
            uo.z = xv.z - acc1[i2][2] - bias;
            uo.w = xv.w - acc1[i2][3] - bias;
            bo.x = acc2[i2][0]; bo.y = acc2[i2][1];
            bo.z = acc2[i2][2]; bo.w = acc2[i2][3];
            *(float4*)&U [(size_t)n * FMAP + o * PP + p0] = uo;
            *(float4*)&Bm[(size_t)n * FMAP + o * PP + p0] = bo;
        }
    }
}

// ---------------------------------------------------------------------------
// K_post: 320 blocks x 256 threads.
//   blocks [0,256):  dist role — 4x4 pair tiles, register abs-diff.
//   blocks [256,320): out role — reduce part + bias, broadcast 16 n-rows each.
// ---------------------------------------------------------------------------
__global__ __launch_bounds__(256) void k_post(const float* __restrict__ U,
                                              const float* __restrict__ Bm,
                                              const float* __restrict__ part,
                                              const float* __restrict__ bg,
                                              float* __restrict__ out,
                                              float* __restrict__ edges) {
    const int t = threadIdx.x;
    if (blockIdx.x < 256) {
        const int i0 = (blockIdx.x >> 4) * 4;
        const int j0 = (blockIdx.x & 15) * 4;

        float acc[4][4] = {{0.f}};
        #pragma unroll
        for (int s = 0; s < 4; ++s) {
            const int m = s * 1024 + t * 4;
            float4 u[4], b[4];
            #pragma unroll
            for (int jl = 0; jl < 4; ++jl) u[jl] = *(const float4*)&U [(size_t)(j0 + jl) * FMAP + m];
            #pragma unroll
            for (int il = 0; il < 4; ++il) b[il] = *(const float4*)&Bm[(size_t)(i0 + il) * FMAP + m];
            #pragma unroll
            for (int il = 0; il < 4; ++il)
                #pragma unroll
                for (int jl = 0; jl < 4; ++jl) {
                    acc[il][jl] += fabsf(u[jl].x - b[il].x) + fabsf(u[jl].y - b[il].y)
                                 + fabsf(u[jl].z - b[il].z) + fabsf(u[jl].w - b[il].w);
                }
        }
        #pragma unroll
        for (int il = 0; il < 4; ++il)
            #pragma unroll
            for (int jl = 0; jl < 4; ++jl) {
                float v = acc[il][jl];
                #pragma unroll
                for (int msk = 1; msk < 64; msk <<= 1) v += __shfl_xor(v, msk, 64);
                acc[il][jl] = v;
            }
        __shared__ float wred[4][16];
        const int w = t >> 6;
        if ((t & 63) == 0) {
            #pragma unroll
            for (int il = 0; il < 4; ++il)
                #pragma unroll
                for (int jl = 0; jl < 4; ++jl) wred[w][il * 4 + jl] = acc[il][jl];
        }
        __syncthreads();
        if (t < 16) {
            const int il = t >> 2, jl = t & 3;
            const int i = i0 + il, j = j0 + jl;
            float v = wred[0][t] + wred[1][t] + wred[2][t] + wred[3][t];
            edges[i * 64 + j] = (i == j) ? 1.0f : v;
        }
    } else {
        // out role: 64 blocks; mb = m-chunk of 256, nb = 16-row n-chunk
        const int b  = blockIdx.x - 256;
        const int mb = b & 15, nb = b >> 4;
        const int m  = mb * 256 + t;
        float s = bg[m];
        #pragma unroll 8
        for (int kb = 0; kb < KCH; ++kb) s += part[(size_t)kb * FMAP + m];
        #pragma unroll
        for (int nn = 0; nn < 16; ++nn)
            out[(size_t)(nb * 16 + nn) * FMAP + m] = s;
    }
}

extern "C" void kernel_launch(void* const* d_in, const int* in_sizes, int n_in,
                              void* d_out, int out_size, void* d_ws, size_t ws_size,
                              hipStream_t stream) {
    const float* x  = (const float*)d_in[0];   // (64,1,256,4,4)
    const float* We = (const float*)d_in[1];   // (256,512)
    const float* be = (const float*)d_in[2];   // (256,)
    const float* Wg = (const float*)d_in[3];   // (4096,4096)
    const float* bg = (const float*)d_in[4];   // (4096,)
    float* out   = (float*)d_out;
    float* edges = out + (size_t)NN * FMAP;

    float* ws   = (float*)d_ws;
    float* U    = ws;                        // 262144 floats
    float* Bm   = U + (size_t)NN * FMAP;     // 262144 floats
    float* part = Bm + (size_t)NN * FMAP;    // 262144 floats (concurrent with U/Bm now)

    k_big <<<dim3(512), 256, 0, stream>>>(x, We, be, Wg, U, Bm, part);
    k_post<<<dim3(320), 256, 0, stream>>>(U, Bm, part, bg, out, edges);
}